// Round 12
// baseline (133.216 us; speedup 1.0000x reference)
//
#include <hip/hip_runtime.h>
#include <hip/hip_fp16.h>

// out[b][f] = sum_{k: rows[k]=f} vals[k] * inputs[b][cols[k]] + bias[f]
//
// R12: BT 512->1024 (32B/lane = 2x dwordx4 fp16 gathers per entry).
//  - entry-visits halve (nnz x 4 bt-tiles), segment-walks halve (64K),
//    scalar pair traffic halves; gather bytes & FMA count unchanged.
//  - dual-stream min/remainder dropped (R11: neutral); sequential walks,
//    MLP=2 from the two independent loads per entry.
//  - keeps: NPHASE=4 quarter phases (2MB/XCD w/ BT=1024), packed+prefetched
//    seg descriptors, fp16 inT + fma_mix, FT=16, bf16 LDS tile, nt stores.
// Setup: fused transpose||hist, scan16k (int4 loads), scatter. 5 launches.

#define NF 4096
#define IND 4096
#define BATCH_TOTAL 4096
#define FT 16
#define BT 1024
#define NT_MAIN 512
#define NPHASE 4
#define NKEYS (NPHASE * NF)                        // 16384
#define NTILES ((IND / 64) * (BATCH_TOTAL / 64))   // 4096 transpose tiles

typedef float f32x4 __attribute__((ext_vector_type(4)));

__device__ __forceinline__ float bf2f(unsigned short u) {
    return __uint_as_float(((unsigned int)u) << 16);
}
__device__ __forceinline__ unsigned short f2bf(float x) {
    unsigned int h = __float_as_uint(x);
    h += 0x7fff + ((h >> 16) & 1);   // round-to-nearest-even
    return (unsigned short)(h >> 16);
}

// ---------- F1: fused transpose->fp16 (blocks 0..NTILES-1) + quarter-hist ----------
__global__ __launch_bounds__(256)
void fused_transpose_hist(const float* __restrict__ in,
                          __half* __restrict__ outT,
                          const int* __restrict__ rows,
                          const int* __restrict__ cols,
                          int* __restrict__ cntq, int nnz) {
    if (blockIdx.x < NTILES) {
        __shared__ float t[64][65];
        const int tb = blockIdx.x;
        const int d0 = (tb & 63) * 64;
        const int b0 = (tb >> 6) * 64;
        const int tx4 = threadIdx.x & 15;
        const int ty  = threadIdx.x >> 4;
#pragma unroll
        for (int p = 0; p < 4; ++p) {
            int brow = ty + p * 16;
            float4 v = *(const float4*)(in + (long)(b0 + brow) * IND + d0 + tx4 * 4);
            t[brow][tx4 * 4 + 0] = v.x;
            t[brow][tx4 * 4 + 1] = v.y;
            t[brow][tx4 * 4 + 2] = v.z;
            t[brow][tx4 * 4 + 3] = v.w;
        }
        __syncthreads();
        const int bx4 = threadIdx.x & 15;
        const int dy  = threadIdx.x >> 4;
#pragma unroll
        for (int p = 0; p < 4; ++p) {
            int drow = dy + p * 16;
            __half h4[4];
            h4[0] = __float2half(t[bx4 * 4 + 0][drow]);
            h4[1] = __float2half(t[bx4 * 4 + 1][drow]);
            h4[2] = __float2half(t[bx4 * 4 + 2][drow]);
            h4[3] = __float2half(t[bx4 * 4 + 3][drow]);
            *(ushort4*)(outT + (long)(d0 + drow) * BATCH_TOTAL + b0 + bx4 * 4) =
                *(const ushort4*)h4;
        }
    } else {
        int k = (blockIdx.x - NTILES) * 256 + threadIdx.x;
        if (k < nnz) {
            int key = ((cols[k] >> 10) << 12) | rows[k];   // quarter*4096 + row
            atomicAdd(&cntq[key], 1);
        }
    }
}

// ---------- S1: scan 16384 counts -> seg {start,count} and cursorq ----------
__global__ __launch_bounds__(512)
void scan16k_kernel(const int* __restrict__ cntq, int2* __restrict__ seg,
                    int* __restrict__ cursorq) {
    __shared__ int ts[512];
    const int t = threadIdx.x;
    const int base = t * 32;
    int e[32];
#pragma unroll
    for (int i = 0; i < 8; ++i)
        *(int4*)&e[i * 4] = *(const int4*)&cntq[base + i * 4];
    int tot = 0;
#pragma unroll
    for (int i = 0; i < 32; ++i) tot += e[i];
    ts[t] = tot;
    __syncthreads();
    for (int off = 1; off < 512; off <<= 1) {
        int v = (t >= off) ? ts[t - off] : 0;
        __syncthreads();
        ts[t] += v;
        __syncthreads();
    }
    int run = (t == 0) ? 0 : ts[t - 1];
#pragma unroll
    for (int i = 0; i < 32; ++i) {
        seg[base + i] = make_int2(run, e[i]);
        cursorq[base + i] = run;
        run += e[i];
    }
}

// ---------- S2: scatter entries sorted by (quarter, row) ----------
__global__ void scatter_pairsq_kernel(const float* __restrict__ vals,
                                      const int* __restrict__ rows,
                                      const int* __restrict__ cols,
                                      int* __restrict__ cursorq,
                                      int2* __restrict__ pairs, int nnz) {
    int k = blockIdx.x * blockDim.x + threadIdx.x;
    if (k < nnz) {
        int c = cols[k];
        int key = ((c >> 10) << 12) | rows[k];
        int p = atomicAdd(&cursorq[key], 1);
        pairs[p] = make_int2(c, __float_as_int(vals[k]));
    }
}

// ---------- per-segment AXPY walk (2x dwordx4 fp16 gather, fma_mix) ----------
__device__ __forceinline__ void walk_seg(const int2* __restrict__ pairs,
                                         int start, int n,
                                         const __half* __restrict__ gbase,
                                         float* __restrict__ a) {
    for (int k = 0; k < n; ++k) {
        int2 e = pairs[start + k];                       // uniform scalar
        float v = __int_as_float(e.y);
        const __half* g = gbase + (long)e.x * BATCH_TOTAL;
        union { uint4 u; __half h[8]; } U0, U1;
        U0.u = *(const uint4*)(g);                       // 2 independent loads
        U1.u = *(const uint4*)(g + 8);
#pragma unroll
        for (int j = 0; j < 8; ++j)
            a[j] += v * __half2float(U0.h[j]);           // v_fma_mix_f32
#pragma unroll
        for (int j = 0; j < 8; ++j)
            a[8 + j] += v * __half2float(U1.h[j]);
    }
}

// ---------- K4: main CSR-AXPY (quarter-phased, BT=1024) ----------
__global__ __launch_bounds__(NT_MAIN, 8)
void spmm_axpy_kernel(const __half* __restrict__ inT,
                      const int2* __restrict__ pairs,
                      const int2* __restrict__ seg,
                      const float* __restrict__ bias,
                      float* __restrict__ out) {
#pragma clang fp contract(fast)
    __shared__ unsigned short tile[FT][BT + 8];  // 33 KB -> 4 blocks/CU

    // XCD-chunked bijective swizzle (nwg = 1024); fblk fastest within chunk.
    const int bid = blockIdx.x;
    const int per = gridDim.x >> 3;            // 128
    const int wg = (bid & 7) * per + (bid >> 3);
    const int fblk = wg & (NF / FT - 1);       // 0..255
    const int bt   = wg >> 8;                  // 0..3
    const int b0 = bt * BT;
    const int fbase = fblk * FT;

    const int tid = threadIdx.x;
    const int wid = tid >> 6;                  // 0..7
    const int lane = tid & 63;

    const int fA = fbase + wid;                // features fbase+0..7
    const int fB = fbase + 8 + wid;            // features fbase+8..15

    // Prefetch ALL segment descriptors up front (8 independent s_loads).
    int sA[NPHASE], nA[NPHASE], sB[NPHASE], nB[NPHASE];
#pragma unroll
    for (int h = 0; h < NPHASE; ++h) {
        int2 dA = seg[h * NF + fA];
        int2 dB = seg[h * NF + fB];
        sA[h] = __builtin_amdgcn_readfirstlane(dA.x);
        nA[h] = __builtin_amdgcn_readfirstlane(dA.y);
        sB[h] = __builtin_amdgcn_readfirstlane(dB.x);
        nB[h] = __builtin_amdgcn_readfirstlane(dB.y);
    }

    float aA[16], aB[16];
#pragma unroll
    for (int j = 0; j < 16; ++j) { aA[j] = 0.f; aB[j] = 0.f; }
    const __half* gbase = inT + b0 + lane * 16;

#pragma unroll
    for (int h = 0; h < NPHASE; ++h) {         // col-quarter phases (outer)
        walk_seg(pairs, sA[h], nA[h], gbase, aA);
        walk_seg(pairs, sB[h], nB[h], gbase, aB);
    }

    // Pack acc -> bf16 tile (32B/lane contiguous).
    ushort4 q[4];
#pragma unroll
    for (int j = 0; j < 4; ++j) {
        q[j].x = f2bf(aA[j * 4 + 0]);
        q[j].y = f2bf(aA[j * 4 + 1]);
        q[j].z = f2bf(aA[j * 4 + 2]);
        q[j].w = f2bf(aA[j * 4 + 3]);
    }
#pragma unroll
    for (int j = 0; j < 4; ++j)
        *(ushort4*)(&tile[wid][lane * 16 + j * 4]) = q[j];
#pragma unroll
    for (int j = 0; j < 4; ++j) {
        q[j].x = f2bf(aB[j * 4 + 0]);
        q[j].y = f2bf(aB[j * 4 + 1]);
        q[j].z = f2bf(aB[j * 4 + 2]);
        q[j].w = f2bf(aB[j * 4 + 3]);
    }
#pragma unroll
    for (int j = 0; j < 4; ++j)
        *(ushort4*)(&tile[wid + 8][lane * 16 + j * 4]) = q[j];
    __syncthreads();

    // Epilogue: out[b0+r][fbase..fbase+15] = tile[.][r] + bias, coalesced nt.
    const int chunk = tid & 3;                 // 4 f32x4 across 16 f
    const int rbase = tid >> 2;                // 128 rows of b per iter
    float4 bv = ((const float4*)bias)[(fbase >> 2) + chunk];
#pragma unroll
    for (int p = 0; p < 8; ++p) {
        int r = rbase + p * 128;
        f32x4 o;
        o.x = bf2f(tile[chunk * 4 + 0][r]) + bv.x;
        o.y = bf2f(tile[chunk * 4 + 1][r]) + bv.y;
        o.z = bf2f(tile[chunk * 4 + 2][r]) + bv.z;
        o.w = bf2f(tile[chunk * 4 + 3][r]) + bv.w;
        __builtin_nontemporal_store(
            o, (f32x4*)(out + (long)(b0 + r) * NF + fbase + chunk * 4));
    }
}

// ---------- Fallback (R2 structure) if ws too small ----------
__global__ void init_out_kernel(float* __restrict__ out,
                                const float* __restrict__ bias) {
    const int nf4 = NF / 4;
    const long total = (long)BATCH_TOTAL * nf4;
    const float4* b4 = (const float4*)bias;
    float4* o4 = (float4*)out;
    for (long i = (long)blockIdx.x * blockDim.x + threadIdx.x; i < total;
         i += (long)gridDim.x * blockDim.x)
        o4[i] = b4[i & (nf4 - 1)];
}

__global__ void hist_kernel(const int* __restrict__ rows,
                            int* __restrict__ cnt, int nnz) {
    int k = blockIdx.x * blockDim.x + threadIdx.x;
    if (k < nnz) atomicAdd(&cnt[rows[k]], 1);
}

__global__ __launch_bounds__(1024)
void scan_kernel(const int* __restrict__ cnt, int* __restrict__ rptr,
                 int* __restrict__ cursor) {
    __shared__ int ts[1024];
    const int t = threadIdx.x;
    const int base = t * 4;
    int e0 = cnt[base], e1 = cnt[base + 1], e2 = cnt[base + 2], e3 = cnt[base + 3];
    ts[t] = e0 + e1 + e2 + e3;
    __syncthreads();
    for (int off = 1; off < 1024; off <<= 1) {
        int v = (t >= off) ? ts[t - off] : 0;
        __syncthreads();
        ts[t] += v;
        __syncthreads();
    }
    int excl = (t == 0) ? 0 : ts[t - 1];
    int p0 = excl, p1 = excl + e0, p2 = p1 + e1, p3 = p2 + e2;
    rptr[base + 0] = p0;   cursor[base + 0] = p0;
    rptr[base + 1] = p1;   cursor[base + 1] = p1;
    rptr[base + 2] = p2;   cursor[base + 2] = p2;
    rptr[base + 3] = p3;   cursor[base + 3] = p3;
}

__global__ void scatter3_kernel(const float* __restrict__ vals,
                                const int* __restrict__ rows,
                                const int* __restrict__ cols,
                                int* __restrict__ cursor,
                                float* __restrict__ sval,
                                int* __restrict__ scol,
                                int* __restrict__ srow, int nnz) {
    int k = blockIdx.x * blockDim.x + threadIdx.x;
    if (k < nnz) {
        int r = rows[k];
        int p = atomicAdd(&cursor[r], 1);
        sval[p] = vals[k];
        scol[p] = cols[k];
        srow[p] = r;
    }
}

#define TILE_B_FB 4
__global__ __launch_bounds__(512, 4)
void spmm_csr_fb_kernel(const float* __restrict__ inputs,
                        const float* __restrict__ sval,
                        const int* __restrict__ scol,
                        const int* __restrict__ srow,
                        float* __restrict__ out, int nnz) {
    __shared__ float in_lds[TILE_B_FB][IND];
    const int tid = threadIdx.x;
    const long b0 = (long)blockIdx.x * TILE_B_FB;
    for (int i = tid; i < IND / 4; i += 512) {
#pragma unroll
        for (int j = 0; j < TILE_B_FB; ++j)
            ((float4*)in_lds[j])[i] = ((const float4*)(inputs + (b0 + j) * IND))[i];
    }
    __syncthreads();
    const int C = (nnz + 511) / 512;
    int k0 = tid * C, k1 = min(k0 + C, nnz);
    if (k0 < k1) {
        int cur = srow[k0];
        float a0 = 0.f, a1 = 0.f, a2 = 0.f, a3 = 0.f;
        for (int k = k0; k < k1; ++k) {
            int r = srow[k];
            float v = sval[k];
            int c = scol[k];
            if (r != cur) {
                atomicAdd(&out[(b0 + 0) * NF + cur], a0);
                atomicAdd(&out[(b0 + 1) * NF + cur], a1);
                atomicAdd(&out[(b0 + 2) * NF + cur], a2);
                atomicAdd(&out[(b0 + 3) * NF + cur], a3);
                a0 = a1 = a2 = a3 = 0.f;
                cur = r;
            }
            a0 += v * in_lds[0][c];
            a1 += v * in_lds[1][c];
            a2 += v * in_lds[2][c];
            a3 += v * in_lds[3][c];
        }
        atomicAdd(&out[(b0 + 0) * NF + cur], a0);
        atomicAdd(&out[(b0 + 1) * NF + cur], a1);
        atomicAdd(&out[(b0 + 2) * NF + cur], a2);
        atomicAdd(&out[(b0 + 3) * NF + cur], a3);
    }
}

extern "C" void kernel_launch(void* const* d_in, const int* in_sizes, int n_in,
                              void* d_out, int out_size, void* d_ws, size_t ws_size,
                              hipStream_t stream) {
    const float* inputs = (const float*)d_in[0];
    const float* vals   = (const float*)d_in[1];
    const int*   rows   = (const int*)d_in[2];
    const int*   cols   = (const int*)d_in[3];
    const float* bias   = (const float*)d_in[4];
    float* out = (float*)d_out;
    const int nnz = in_sizes[1];

    char* ws = (char*)d_ws;
    size_t off = 0;
    int*  cntq    = (int*)(ws + off);  off += (size_t)NKEYS * 4;   // 64 KB
    int*  cursorq = (int*)(ws + off);  off += (size_t)NKEYS * 4;   // 64 KB
    int2* seg     = (int2*)(ws + off); off += (size_t)NKEYS * 8;   // 128 KB
    size_t pairs_off = (off + 15) & ~(size_t)15;
    int2* pairs = (int2*)(ws + pairs_off);
    size_t after_pairs = (pairs_off + (size_t)nnz * 8 + 15) & ~(size_t)15;
    __half* inT = (__half*)(ws + after_pairs);
    size_t need_main = after_pairs + (size_t)IND * BATCH_TOTAL * 2;

    const int eb = (nnz + 255) / 256;

    if (need_main <= ws_size) {
        (void)hipMemsetAsync(cntq, 0, (size_t)NKEYS * 4, stream);
        fused_transpose_hist<<<NTILES + eb, 256, 0, stream>>>(
            inputs, inT, rows, cols, cntq, nnz);
        scan16k_kernel<<<1, 512, 0, stream>>>(cntq, seg, cursorq);
        scatter_pairsq_kernel<<<eb, 256, 0, stream>>>(vals, rows, cols, cursorq,
                                                      pairs, nnz);
        spmm_axpy_kernel<<<(NF / FT) * (BATCH_TOTAL / BT), NT_MAIN, 0, stream>>>(
            inT, pairs, seg, bias, out);
    } else {
        // Fallback: R2 structure (needs ~2.1 MB of ws).
        int* cnt    = cntq;
        int* cursor = cursorq;
        int* rptr   = (int*)seg;
        int*   srow = (int*)(ws + pairs_off);
        int*   scol = srow + nnz;
        float* sval = (float*)(scol + nnz);
        (void)hipMemsetAsync(cnt, 0, (size_t)NF * 4, stream);
        init_out_kernel<<<2048, 256, 0, stream>>>(out, bias);
        hist_kernel<<<eb, 256, 0, stream>>>(rows, cnt, nnz);
        scan_kernel<<<1, 1024, 0, stream>>>(cnt, rptr, cursor);
        scatter3_kernel<<<eb, 256, 0, stream>>>(vals, rows, cols, cursor,
                                                sval, scol, srow, nnz);
        spmm_csr_fb_kernel<<<BATCH_TOTAL / TILE_B_FB, 512, 0, stream>>>(
            inputs, sval, scol, srow, out, nnz);
    }
}

// Round 13
// 117.074 us; speedup vs baseline: 1.1379x; 1.1379x over previous
//
#include <hip/hip_runtime.h>
#include <hip/hip_fp16.h>

// out[b][f] = sum_{k: rows[k]=f} vals[k] * inputs[b][cols[k]] + bias[f]
//
// R13: best-of composition (no new structure):
//  - main: BT=512 (16B/lane contiguous gathers - R12 proved wider strided
//    gathers regress), NPHASE=2 halves (R9's fastest), FT=16, fp16 inT +
//    fma_mix, packed {start,count} seg descriptors prefetched at block top
//    (R11's transition fix), sequential segment walks, bf16 LDS tile,
//    nontemporal f32 stores.
//  - setup: fused transpose||hist (half-key), scan8k -> int2 seg, scatter.
// 5 launches.

#define NF 4096
#define IND 4096
#define BATCH_TOTAL 4096
#define FT 16
#define BT 512
#define NT_MAIN 512
#define NPHASE 2
#define NKEYS (NPHASE * NF)                        // 8192
#define NTILES ((IND / 64) * (BATCH_TOTAL / 64))   // 4096 transpose tiles

typedef float f32x4 __attribute__((ext_vector_type(4)));

__device__ __forceinline__ float bf2f(unsigned short u) {
    return __uint_as_float(((unsigned int)u) << 16);
}
__device__ __forceinline__ unsigned short f2bf(float x) {
    unsigned int h = __float_as_uint(x);
    h += 0x7fff + ((h >> 16) & 1);   // round-to-nearest-even
    return (unsigned short)(h >> 16);
}

// ---------- F1: fused transpose->fp16 (blocks 0..NTILES-1) + half-hist ----------
__global__ __launch_bounds__(256)
void fused_transpose_hist(const float* __restrict__ in,
                          __half* __restrict__ outT,
                          const int* __restrict__ rows,
                          const int* __restrict__ cols,
                          int* __restrict__ cnt2, int nnz) {
    if (blockIdx.x < NTILES) {
        __shared__ float t[64][65];
        const int tb = blockIdx.x;
        const int d0 = (tb & 63) * 64;
        const int b0 = (tb >> 6) * 64;
        const int tx4 = threadIdx.x & 15;
        const int ty  = threadIdx.x >> 4;
#pragma unroll
        for (int p = 0; p < 4; ++p) {
            int brow = ty + p * 16;
            float4 v = *(const float4*)(in + (long)(b0 + brow) * IND + d0 + tx4 * 4);
            t[brow][tx4 * 4 + 0] = v.x;
            t[brow][tx4 * 4 + 1] = v.y;
            t[brow][tx4 * 4 + 2] = v.z;
            t[brow][tx4 * 4 + 3] = v.w;
        }
        __syncthreads();
        const int bx4 = threadIdx.x & 15;
        const int dy  = threadIdx.x >> 4;
#pragma unroll
        for (int p = 0; p < 4; ++p) {
            int drow = dy + p * 16;
            __half h4[4];
            h4[0] = __float2half(t[bx4 * 4 + 0][drow]);
            h4[1] = __float2half(t[bx4 * 4 + 1][drow]);
            h4[2] = __float2half(t[bx4 * 4 + 2][drow]);
            h4[3] = __float2half(t[bx4 * 4 + 3][drow]);
            *(ushort4*)(outT + (long)(d0 + drow) * BATCH_TOTAL + b0 + bx4 * 4) =
                *(const ushort4*)h4;
        }
    } else {
        int k = (blockIdx.x - NTILES) * 256 + threadIdx.x;
        if (k < nnz) {
            int key = ((cols[k] >> 11) << 12) | rows[k];   // half*4096 + row
            atomicAdd(&cnt2[key], 1);
        }
    }
}

// ---------- S1: scan 8192 counts -> seg {start,count} and cursor ----------
__global__ __launch_bounds__(512)
void scan8k_kernel(const int* __restrict__ cnt2, int2* __restrict__ seg,
                   int* __restrict__ cursor2) {
    __shared__ int ts[512];
    const int t = threadIdx.x;
    const int base = t * 16;
    int e[16];
#pragma unroll
    for (int i = 0; i < 4; ++i)
        *(int4*)&e[i * 4] = *(const int4*)&cnt2[base + i * 4];
    int tot = 0;
#pragma unroll
    for (int i = 0; i < 16; ++i) tot += e[i];
    ts[t] = tot;
    __syncthreads();
    for (int off = 1; off < 512; off <<= 1) {
        int v = (t >= off) ? ts[t - off] : 0;
        __syncthreads();
        ts[t] += v;
        __syncthreads();
    }
    int run = (t == 0) ? 0 : ts[t - 1];
#pragma unroll
    for (int i = 0; i < 16; ++i) {
        seg[base + i] = make_int2(run, e[i]);
        cursor2[base + i] = run;
        run += e[i];
    }
}

// ---------- S2: scatter entries sorted by (half, row) ----------
__global__ void scatter_pairs2_kernel(const float* __restrict__ vals,
                                      const int* __restrict__ rows,
                                      const int* __restrict__ cols,
                                      int* __restrict__ cursor2,
                                      int2* __restrict__ pairs, int nnz) {
    int k = blockIdx.x * blockDim.x + threadIdx.x;
    if (k < nnz) {
        int c = cols[k];
        int key = ((c >> 11) << 12) | rows[k];
        int p = atomicAdd(&cursor2[key], 1);
        pairs[p] = make_int2(c, __float_as_int(vals[k]));
    }
}

// ---------- per-segment AXPY walk (fp16 dwordx4 gather, fma_mix) ----------
__device__ __forceinline__ void walk_seg(const int2* __restrict__ pairs,
                                         int start, int n,
                                         const __half* __restrict__ gbase,
                                         float* __restrict__ a) {
#pragma unroll 4
    for (int k = 0; k < n; ++k) {
        int2 e = pairs[start + k];                       // uniform scalar
        float v = __int_as_float(e.y);
        union { uint4 u; __half h[8]; } U;
        U.u = *(const uint4*)(gbase + (long)e.x * BATCH_TOTAL);
#pragma unroll
        for (int j = 0; j < 8; ++j)
            a[j] += v * __half2float(U.h[j]);            // v_fma_mix_f32
    }
}

// ---------- K4: main CSR-AXPY (half-phased, BT=512) ----------
__global__ __launch_bounds__(NT_MAIN, 8)
void spmm_axpy_kernel(const __half* __restrict__ inT,
                      const int2* __restrict__ pairs,
                      const int2* __restrict__ seg,
                      const float* __restrict__ bias,
                      float* __restrict__ out) {
#pragma clang fp contract(fast)
    __shared__ unsigned short tile[FT][BT + 8];  // 16.6 KB -> 4 blocks/CU

    // XCD-chunked bijective swizzle (nwg = 2048); fblk fastest within chunk.
    const int bid = blockIdx.x;
    const int per = gridDim.x >> 3;            // 256
    const int wg = (bid & 7) * per + (bid >> 3);
    const int fblk = wg & (NF / FT - 1);       // 0..255
    const int bt   = wg >> 8;                  // 0..7
    const int b0 = bt * BT;
    const int fbase = fblk * FT;

    const int tid = threadIdx.x;
    const int wid = tid >> 6;                  // 0..7
    const int lane = tid & 63;

    const int fA = fbase + wid;                // features fbase+0..7
    const int fB = fbase + 8 + wid;            // features fbase+8..15

    // Prefetch ALL segment descriptors up front (4 independent s_loads).
    int sA[NPHASE], nA[NPHASE], sB[NPHASE], nB[NPHASE];
#pragma unroll
    for (int h = 0; h < NPHASE; ++h) {
        int2 dA = seg[h * NF + fA];
        int2 dB = seg[h * NF + fB];
        sA[h] = __builtin_amdgcn_readfirstlane(dA.x);
        nA[h] = __builtin_amdgcn_readfirstlane(dA.y);
        sB[h] = __builtin_amdgcn_readfirstlane(dB.x);
        nB[h] = __builtin_amdgcn_readfirstlane(dB.y);
    }

    float aA[8] = {0.f, 0.f, 0.f, 0.f, 0.f, 0.f, 0.f, 0.f};
    float aB[8] = {0.f, 0.f, 0.f, 0.f, 0.f, 0.f, 0.f, 0.f};
    const __half* gbase = inT + b0 + lane * 8;

#pragma unroll
    for (int h = 0; h < NPHASE; ++h) {         // col-half phases (outer)
        walk_seg(pairs, sA[h], nA[h], gbase, aA);
        walk_seg(pairs, sB[h], nB[h], gbase, aB);
    }

    ushort4 p0, p1;
    p0.x = f2bf(aA[0]); p0.y = f2bf(aA[1]); p0.z = f2bf(aA[2]); p0.w = f2bf(aA[3]);
    p1.x = f2bf(aA[4]); p1.y = f2bf(aA[5]); p1.z = f2bf(aA[6]); p1.w = f2bf(aA[7]);
    *(ushort4*)(&tile[wid][lane * 8])     = p0;
    *(ushort4*)(&tile[wid][lane * 8 + 4]) = p1;
    p0.x = f2bf(aB[0]); p0.y = f2bf(aB[1]); p0.z = f2bf(aB[2]); p0.w = f2bf(aB[3]);
    p1.x = f2bf(aB[4]); p1.y = f2bf(aB[5]); p1.z = f2bf(aB[6]); p1.w = f2bf(aB[7]);
    *(ushort4*)(&tile[wid + 8][lane * 8])     = p0;
    *(ushort4*)(&tile[wid + 8][lane * 8 + 4]) = p1;
    __syncthreads();

    // Epilogue: out[b0+r][fbase..fbase+15] = tile[.][r] + bias, coalesced nt.
    const int chunk = tid & 3;                 // 4 f32x4 across 16 f
    const int rbase = tid >> 2;                // 128 rows of b per iter
    float4 bv = ((const float4*)bias)[(fbase >> 2) + chunk];
#pragma unroll
    for (int p = 0; p < 4; ++p) {
        int r = rbase + p * 128;
        f32x4 o;
        o.x = bf2f(tile[chunk * 4 + 0][r]) + bv.x;
        o.y = bf2f(tile[chunk * 4 + 1][r]) + bv.y;
        o.z = bf2f(tile[chunk * 4 + 2][r]) + bv.z;
        o.w = bf2f(tile[chunk * 4 + 3][r]) + bv.w;
        __builtin_nontemporal_store(
            o, (f32x4*)(out + (long)(b0 + r) * NF + fbase + chunk * 4));
    }
}

// ---------- Fallback (R2 structure) if ws too small ----------
__global__ void init_out_kernel(float* __restrict__ out,
                                const float* __restrict__ bias) {
    const int nf4 = NF / 4;
    const long total = (long)BATCH_TOTAL * nf4;
    const float4* b4 = (const float4*)bias;
    float4* o4 = (float4*)out;
    for (long i = (long)blockIdx.x * blockDim.x + threadIdx.x; i < total;
         i += (long)gridDim.x * blockDim.x)
        o4[i] = b4[i & (nf4 - 1)];
}

__global__ void hist_kernel(const int* __restrict__ rows,
                            int* __restrict__ cnt, int nnz) {
    int k = blockIdx.x * blockDim.x + threadIdx.x;
    if (k < nnz) atomicAdd(&cnt[rows[k]], 1);
}

__global__ __launch_bounds__(1024)
void scan_kernel(const int* __restrict__ cnt, int* __restrict__ rptr,
                 int* __restrict__ cursor) {
    __shared__ int ts[1024];
    const int t = threadIdx.x;
    const int base = t * 4;
    int e0 = cnt[base], e1 = cnt[base + 1], e2 = cnt[base + 2], e3 = cnt[base + 3];
    ts[t] = e0 + e1 + e2 + e3;
    __syncthreads();
    for (int off = 1; off < 1024; off <<= 1) {
        int v = (t >= off) ? ts[t - off] : 0;
        __syncthreads();
        ts[t] += v;
        __syncthreads();
    }
    int excl = (t == 0) ? 0 : ts[t - 1];
    int p0 = excl, p1 = excl + e0, p2 = p1 + e1, p3 = p2 + e2;
    rptr[base + 0] = p0;   cursor[base + 0] = p0;
    rptr[base + 1] = p1;   cursor[base + 1] = p1;
    rptr[base + 2] = p2;   cursor[base + 2] = p2;
    rptr[base + 3] = p3;   cursor[base + 3] = p3;
}

__global__ void scatter3_kernel(const float* __restrict__ vals,
                                const int* __restrict__ rows,
                                const int* __restrict__ cols,
                                int* __restrict__ cursor,
                                float* __restrict__ sval,
                                int* __restrict__ scol,
                                int* __restrict__ srow, int nnz) {
    int k = blockIdx.x * blockDim.x + threadIdx.x;
    if (k < nnz) {
        int r = rows[k];
        int p = atomicAdd(&cursor[r], 1);
        sval[p] = vals[k];
        scol[p] = cols[k];
        srow[p] = r;
    }
}

#define TILE_B_FB 4
__global__ __launch_bounds__(512, 4)
void spmm_csr_fb_kernel(const float* __restrict__ inputs,
                        const float* __restrict__ sval,
                        const int* __restrict__ scol,
                        const int* __restrict__ srow,
                        float* __restrict__ out, int nnz) {
    __shared__ float in_lds[TILE_B_FB][IND];
    const int tid = threadIdx.x;
    const long b0 = (long)blockIdx.x * TILE_B_FB;
    for (int i = tid; i < IND / 4; i += 512) {
#pragma unroll
        for (int j = 0; j < TILE_B_FB; ++j)
            ((float4*)in_lds[j])[i] = ((const float4*)(inputs + (b0 + j) * IND))[i];
    }
    __syncthreads();
    const int C = (nnz + 511) / 512;
    int k0 = tid * C, k1 = min(k0 + C, nnz);
    if (k0 < k1) {
        int cur = srow[k0];
        float a0 = 0.f, a1 = 0.f, a2 = 0.f, a3 = 0.f;
        for (int k = k0; k < k1; ++k) {
            int r = srow[k];
            float v = sval[k];
            int c = scol[k];
            if (r != cur) {
                atomicAdd(&out[(b0 + 0) * NF + cur], a0);
                atomicAdd(&out[(b0 + 1) * NF + cur], a1);
                atomicAdd(&out[(b0 + 2) * NF + cur], a2);
                atomicAdd(&out[(b0 + 3) * NF + cur], a3);
                a0 = a1 = a2 = a3 = 0.f;
                cur = r;
            }
            a0 += v * in_lds[0][c];
            a1 += v * in_lds[1][c];
            a2 += v * in_lds[2][c];
            a3 += v * in_lds[3][c];
        }
        atomicAdd(&out[(b0 + 0) * NF + cur], a0);
        atomicAdd(&out[(b0 + 1) * NF + cur], a1);
        atomicAdd(&out[(b0 + 2) * NF + cur], a2);
        atomicAdd(&out[(b0 + 3) * NF + cur], a3);
    }
}

extern "C" void kernel_launch(void* const* d_in, const int* in_sizes, int n_in,
                              void* d_out, int out_size, void* d_ws, size_t ws_size,
                              hipStream_t stream) {
    const float* inputs = (const float*)d_in[0];
    const float* vals   = (const float*)d_in[1];
    const int*   rows   = (const int*)d_in[2];
    const int*   cols   = (const int*)d_in[3];
    const float* bias   = (const float*)d_in[4];
    float* out = (float*)d_out;
    const int nnz = in_sizes[1];

    char* ws = (char*)d_ws;
    size_t off = 0;
    int*  cnt2    = (int*)(ws + off);  off += (size_t)NKEYS * 4;   // 32 KB
    int*  cursor2 = (int*)(ws + off);  off += (size_t)NKEYS * 4;   // 32 KB
    int2* seg     = (int2*)(ws + off); off += (size_t)NKEYS * 8;   // 64 KB
    size_t pairs_off = (off + 15) & ~(size_t)15;
    int2* pairs = (int2*)(ws + pairs_off);
    size_t after_pairs = (pairs_off + (size_t)nnz * 8 + 15) & ~(size_t)15;
    __half* inT = (__half*)(ws + after_pairs);
    size_t need_main = after_pairs + (size_t)IND * BATCH_TOTAL * 2;

    const int eb = (nnz + 255) / 256;

    if (need_main <= ws_size) {
        (void)hipMemsetAsync(cnt2, 0, (size_t)NKEYS * 4, stream);
        fused_transpose_hist<<<NTILES + eb, 256, 0, stream>>>(
            inputs, inT, rows, cols, cnt2, nnz);
        scan8k_kernel<<<1, 512, 0, stream>>>(cnt2, seg, cursor2);
        scatter_pairs2_kernel<<<eb, 256, 0, stream>>>(vals, rows, cols, cursor2,
                                                      pairs, nnz);
        spmm_axpy_kernel<<<(NF / FT) * (BATCH_TOTAL / BT), NT_MAIN, 0, stream>>>(
            inT, pairs, seg, bias, out);
    } else {
        // Fallback: R2 structure (needs ~2.1 MB of ws).
        int* cnt    = cnt2;
        int* cursor = cursor2;
        int* rptr   = (int*)seg;
        int*   srow = (int*)(ws + pairs_off);
        int*   scol = srow + nnz;
        float* sval = (float*)(scol + nnz);
        (void)hipMemsetAsync(cnt, 0, (size_t)NF * 4, stream);
        init_out_kernel<<<2048, 256, 0, stream>>>(out, bias);
        hist_kernel<<<eb, 256, 0, stream>>>(rows, cnt, nnz);
        scan_kernel<<<1, 1024, 0, stream>>>(cnt, rptr, cursor);
        scatter3_kernel<<<eb, 256, 0, stream>>>(vals, rows, cols, cursor,
                                                sval, scol, srow, nnz);
        spmm_csr_fb_kernel<<<BATCH_TOTAL / TILE_B_FB, 512, 0, stream>>>(
            inputs, sval, scol, srow, out, nnz);
    }
}

// Round 14
// 115.974 us; speedup vs baseline: 1.1487x; 1.0095x over previous
//
#include <hip/hip_runtime.h>
#include <hip/hip_fp16.h>

// out[b][f] = sum_{k: rows[k]=f} vals[k] * inputs[b][cols[k]] + bias[f]
//
// R14: padded-CSR setup — kills hist + scan kernels.
//  - scatter writes pairs[key*CAP + atomicAdd(cnt[key],1)] (CAP=96 >> max
//    count ~45); overflow (never in practice) goes to a tail list drained
//    by every main block (one scalar read when empty).
//  - setup = memset(33KB) + ONE fused transpose||scatter kernel. 3 dispatches.
//  - main kernel: identical to R13 (77us plateau: BT=512, NPHASE=2 halves,
//    FT=16, fp16 inT + fma_mix, prefetched descriptors now from cnt with
//    start=key*CAP, bf16 LDS tile, nontemporal f32 stores).

#define NF 4096
#define IND 4096
#define BATCH_TOTAL 4096
#define FT 16
#define BT 512
#define NT_MAIN 512
#define NPHASE 2
#define NKEYS (NPHASE * NF)                        // 8192
#define CAP 96
#define TAILCAP 4096
#define NTILES ((IND / 64) * (BATCH_TOTAL / 64))   // 4096 transpose tiles

typedef float f32x4 __attribute__((ext_vector_type(4)));

__device__ __forceinline__ float bf2f(unsigned short u) {
    return __uint_as_float(((unsigned int)u) << 16);
}
__device__ __forceinline__ unsigned short f2bf(float x) {
    unsigned int h = __float_as_uint(x);
    h += 0x7fff + ((h >> 16) & 1);   // round-to-nearest-even
    return (unsigned short)(h >> 16);
}

// ---------- F1: fused transpose->fp16 (blocks 0..NTILES-1) + padded scatter ----------
__global__ __launch_bounds__(256)
void fused_transpose_scatter(const float* __restrict__ in,
                             __half* __restrict__ outT,
                             const float* __restrict__ vals,
                             const int* __restrict__ rows,
                             const int* __restrict__ cols,
                             int* __restrict__ cnt,      // [NKEYS+1], last = tail count
                             int2* __restrict__ pairs,   // [NKEYS*CAP]
                             int4* __restrict__ tail,    // [TAILCAP]
                             int nnz) {
    if (blockIdx.x < NTILES) {
        __shared__ float t[64][65];
        const int tb = blockIdx.x;
        const int d0 = (tb & 63) * 64;
        const int b0 = (tb >> 6) * 64;
        const int tx4 = threadIdx.x & 15;
        const int ty  = threadIdx.x >> 4;
#pragma unroll
        for (int p = 0; p < 4; ++p) {
            int brow = ty + p * 16;
            float4 v = *(const float4*)(in + (long)(b0 + brow) * IND + d0 + tx4 * 4);
            t[brow][tx4 * 4 + 0] = v.x;
            t[brow][tx4 * 4 + 1] = v.y;
            t[brow][tx4 * 4 + 2] = v.z;
            t[brow][tx4 * 4 + 3] = v.w;
        }
        __syncthreads();
        const int bx4 = threadIdx.x & 15;
        const int dy  = threadIdx.x >> 4;
#pragma unroll
        for (int p = 0; p < 4; ++p) {
            int drow = dy + p * 16;
            __half h4[4];
            h4[0] = __float2half(t[bx4 * 4 + 0][drow]);
            h4[1] = __float2half(t[bx4 * 4 + 1][drow]);
            h4[2] = __float2half(t[bx4 * 4 + 2][drow]);
            h4[3] = __float2half(t[bx4 * 4 + 3][drow]);
            *(ushort4*)(outT + (long)(d0 + drow) * BATCH_TOTAL + b0 + bx4 * 4) =
                *(const ushort4*)h4;
        }
    } else {
        int k = (blockIdx.x - NTILES) * 256 + threadIdx.x;
        if (k < nnz) {
            int r = rows[k];
            int c = cols[k];
            float v = vals[k];
            int key = ((c >> 11) << 12) | r;              // half*4096 + row
            int pos = atomicAdd(&cnt[key], 1);
            if (pos < CAP) {
                pairs[key * CAP + pos] = make_int2(c, __float_as_int(v));
            } else {
                int t = atomicAdd(&cnt[NKEYS], 1);        // tail counter
                if (t < TAILCAP)
                    tail[t] = make_int4(r, c, __float_as_int(v), 0);
            }
        }
    }
}

// ---------- per-segment AXPY walk (fp16 dwordx4 gather, fma_mix) ----------
__device__ __forceinline__ void walk_seg(const int2* __restrict__ pairs,
                                         int start, int n,
                                         const __half* __restrict__ gbase,
                                         float* __restrict__ a) {
#pragma unroll 4
    for (int k = 0; k < n; ++k) {
        int2 e = pairs[start + k];                       // uniform scalar
        float v = __int_as_float(e.y);
        union { uint4 u; __half h[8]; } U;
        U.u = *(const uint4*)(gbase + (long)e.x * BATCH_TOTAL);
#pragma unroll
        for (int j = 0; j < 8; ++j)
            a[j] += v * __half2float(U.h[j]);            // v_fma_mix_f32
    }
}

// ---------- K4: main CSR-AXPY (half-phased, BT=512, padded-CSR) ----------
__global__ __launch_bounds__(NT_MAIN, 8)
void spmm_axpy_kernel(const __half* __restrict__ inT,
                      const int2* __restrict__ pairs,
                      const int* __restrict__ cnt,
                      const int4* __restrict__ tail,
                      const float* __restrict__ bias,
                      float* __restrict__ out) {
#pragma clang fp contract(fast)
    __shared__ unsigned short tile[FT][BT + 8];  // 16.6 KB -> 4 blocks/CU

    // XCD-chunked bijective swizzle (nwg = 2048); fblk fastest within chunk.
    const int bid = blockIdx.x;
    const int per = gridDim.x >> 3;            // 256
    const int wg = (bid & 7) * per + (bid >> 3);
    const int fblk = wg & (NF / FT - 1);       // 0..255
    const int bt   = wg >> 8;                  // 0..7
    const int b0 = bt * BT;
    const int fbase = fblk * FT;

    const int tid = threadIdx.x;
    const int wid = tid >> 6;                  // 0..7
    const int lane = tid & 63;

    const int fA = fbase + wid;                // features fbase+0..7
    const int fB = fbase + 8 + wid;            // features fbase+8..15

    // Prefetch descriptors: start = key*CAP (computed), n = min(cnt, CAP).
    int nA[NPHASE], nB[NPHASE];
#pragma unroll
    for (int h = 0; h < NPHASE; ++h) {
        nA[h] = min(__builtin_amdgcn_readfirstlane(cnt[h * NF + fA]), CAP);
        nB[h] = min(__builtin_amdgcn_readfirstlane(cnt[h * NF + fB]), CAP);
    }
    const int tc = min(__builtin_amdgcn_readfirstlane(cnt[NKEYS]), TAILCAP);

    float aA[8] = {0.f, 0.f, 0.f, 0.f, 0.f, 0.f, 0.f, 0.f};
    float aB[8] = {0.f, 0.f, 0.f, 0.f, 0.f, 0.f, 0.f, 0.f};
    const __half* gbase = inT + b0 + lane * 8;

#pragma unroll
    for (int h = 0; h < NPHASE; ++h) {         // col-half phases (outer)
        walk_seg(pairs, (h * NF + fA) * CAP, nA[h], gbase, aA);
        walk_seg(pairs, (h * NF + fB) * CAP, nB[h], gbase, aB);
    }

    // Tail drain (normally tc == 0: one scalar read + skip).
    for (int i = 0; i < tc; ++i) {
        int4 e = tail[i];
        if (e.x == fA) walk_seg(nullptr, 0, 0, gbase, aA),  // no-op keep shape
            ({ int2 p = make_int2(e.y, e.z);
               float v = __int_as_float(p.y);
               union { uint4 u; __half h[8]; } U;
               U.u = *(const uint4*)(gbase + (long)p.x * BATCH_TOTAL);
               for (int j = 0; j < 8; ++j) aA[j] += v * __half2float(U.h[j]); });
        if (e.x == fB) {
            float v = __int_as_float(e.z);
            union { uint4 u; __half h[8]; } U;
            U.u = *(const uint4*)(gbase + (long)e.y * BATCH_TOTAL);
            for (int j = 0; j < 8; ++j) aB[j] += v * __half2float(U.h[j]);
        }
    }

    ushort4 p0, p1;
    p0.x = f2bf(aA[0]); p0.y = f2bf(aA[1]); p0.z = f2bf(aA[2]); p0.w = f2bf(aA[3]);
    p1.x = f2bf(aA[4]); p1.y = f2bf(aA[5]); p1.z = f2bf(aA[6]); p1.w = f2bf(aA[7]);
    *(ushort4*)(&tile[wid][lane * 8])     = p0;
    *(ushort4*)(&tile[wid][lane * 8 + 4]) = p1;
    p0.x = f2bf(aB[0]); p0.y = f2bf(aB[1]); p0.z = f2bf(aB[2]); p0.w = f2bf(aB[3]);
    p1.x = f2bf(aB[4]); p1.y = f2bf(aB[5]); p1.z = f2bf(aB[6]); p1.w = f2bf(aB[7]);
    *(ushort4*)(&tile[wid + 8][lane * 8])     = p0;
    *(ushort4*)(&tile[wid + 8][lane * 8 + 4]) = p1;
    __syncthreads();

    // Epilogue: out[b0+r][fbase..fbase+15] = tile[.][r] + bias, coalesced nt.
    const int chunk = tid & 3;                 // 4 f32x4 across 16 f
    const int rbase = tid >> 2;                // 128 rows of b per iter
    float4 bv = ((const float4*)bias)[(fbase >> 2) + chunk];
#pragma unroll
    for (int p = 0; p < 4; ++p) {
        int r = rbase + p * 128;
        f32x4 o;
        o.x = bf2f(tile[chunk * 4 + 0][r]) + bv.x;
        o.y = bf2f(tile[chunk * 4 + 1][r]) + bv.y;
        o.z = bf2f(tile[chunk * 4 + 2][r]) + bv.z;
        o.w = bf2f(tile[chunk * 4 + 3][r]) + bv.w;
        __builtin_nontemporal_store(
            o, (f32x4*)(out + (long)(b0 + r) * NF + fbase + chunk * 4));
    }
}

// ---------- Fallback (R2 structure) if ws too small ----------
__global__ void init_out_kernel(float* __restrict__ out,
                                const float* __restrict__ bias) {
    const int nf4 = NF / 4;
    const long total = (long)BATCH_TOTAL * nf4;
    const float4* b4 = (const float4*)bias;
    float4* o4 = (float4*)out;
    for (long i = (long)blockIdx.x * blockDim.x + threadIdx.x; i < total;
         i += (long)gridDim.x * blockDim.x)
        o4[i] = b4[i & (nf4 - 1)];
}

__global__ void hist_kernel(const int* __restrict__ rows,
                            int* __restrict__ cnt, int nnz) {
    int k = blockIdx.x * blockDim.x + threadIdx.x;
    if (k < nnz) atomicAdd(&cnt[rows[k]], 1);
}

__global__ __launch_bounds__(1024)
void scan_kernel(const int* __restrict__ cnt, int* __restrict__ rptr,
                 int* __restrict__ cursor) {
    __shared__ int ts[1024];
    const int t = threadIdx.x;
    const int base = t * 4;
    int e0 = cnt[base], e1 = cnt[base + 1], e2 = cnt[base + 2], e3 = cnt[base + 3];
    ts[t] = e0 + e1 + e2 + e3;
    __syncthreads();
    for (int off = 1; off < 1024; off <<= 1) {
        int v = (t >= off) ? ts[t - off] : 0;
        __syncthreads();
        ts[t] += v;
        __syncthreads();
    }
    int excl = (t == 0) ? 0 : ts[t - 1];
    int p0 = excl, p1 = excl + e0, p2 = p1 + e1, p3 = p2 + e2;
    rptr[base + 0] = p0;   cursor[base + 0] = p0;
    rptr[base + 1] = p1;   cursor[base + 1] = p1;
    rptr[base + 2] = p2;   cursor[base + 2] = p2;
    rptr[base + 3] = p3;   cursor[base + 3] = p3;
}

__global__ void scatter3_kernel(const float* __restrict__ vals,
                                const int* __restrict__ rows,
                                const int* __restrict__ cols,
                                int* __restrict__ cursor,
                                float* __restrict__ sval,
                                int* __restrict__ scol,
                                int* __restrict__ srow, int nnz) {
    int k = blockIdx.x * blockDim.x + threadIdx.x;
    if (k < nnz) {
        int r = rows[k];
        int p = atomicAdd(&cursor[r], 1);
        sval[p] = vals[k];
        scol[p] = cols[k];
        srow[p] = r;
    }
}

#define TILE_B_FB 4
__global__ __launch_bounds__(512, 4)
void spmm_csr_fb_kernel(const float* __restrict__ inputs,
                        const float* __restrict__ sval,
                        const int* __restrict__ scol,
                        const int* __restrict__ srow,
                        float* __restrict__ out, int nnz) {
    __shared__ float in_lds[TILE_B_FB][IND];
    const int tid = threadIdx.x;
    const long b0 = (long)blockIdx.x * TILE_B_FB;
    for (int i = tid; i < IND / 4; i += 512) {
#pragma unroll
        for (int j = 0; j < TILE_B_FB; ++j)
            ((float4*)in_lds[j])[i] = ((const float4*)(inputs + (b0 + j) * IND))[i];
    }
    __syncthreads();
    const int C = (nnz + 511) / 512;
    int k0 = tid * C, k1 = min(k0 + C, nnz);
    if (k0 < k1) {
        int cur = srow[k0];
        float a0 = 0.f, a1 = 0.f, a2 = 0.f, a3 = 0.f;
        for (int k = k0; k < k1; ++k) {
            int r = srow[k];
            float v = sval[k];
            int c = scol[k];
            if (r != cur) {
                atomicAdd(&out[(b0 + 0) * NF + cur], a0);
                atomicAdd(&out[(b0 + 1) * NF + cur], a1);
                atomicAdd(&out[(b0 + 2) * NF + cur], a2);
                atomicAdd(&out[(b0 + 3) * NF + cur], a3);
                a0 = a1 = a2 = a3 = 0.f;
                cur = r;
            }
            a0 += v * in_lds[0][c];
            a1 += v * in_lds[1][c];
            a2 += v * in_lds[2][c];
            a3 += v * in_lds[3][c];
        }
        atomicAdd(&out[(b0 + 0) * NF + cur], a0);
        atomicAdd(&out[(b0 + 1) * NF + cur], a1);
        atomicAdd(&out[(b0 + 2) * NF + cur], a2);
        atomicAdd(&out[(b0 + 3) * NF + cur], a3);
    }
}

extern "C" void kernel_launch(void* const* d_in, const int* in_sizes, int n_in,
                              void* d_out, int out_size, void* d_ws, size_t ws_size,
                              hipStream_t stream) {
    const float* inputs = (const float*)d_in[0];
    const float* vals   = (const float*)d_in[1];
    const int*   rows   = (const int*)d_in[2];
    const int*   cols   = (const int*)d_in[3];
    const float* bias   = (const float*)d_in[4];
    float* out = (float*)d_out;
    const int nnz = in_sizes[1];

    char* ws = (char*)d_ws;
    size_t off = 0;
    int*  cnt  = (int*)(ws + off);  off += ((size_t)(NKEYS + 1) * 4 + 15) & ~(size_t)15;
    int4* tail = (int4*)(ws + off); off += (size_t)TAILCAP * 16;          // 64 KB
    int2* pairs = (int2*)(ws + off); off += (size_t)NKEYS * CAP * 8;      // 6 MB
    __half* inT = (__half*)(ws + off);
    size_t need_main = off + (size_t)IND * BATCH_TOTAL * 2;               // +32 MB

    const int eb = (nnz + 255) / 256;

    if (need_main <= ws_size) {
        (void)hipMemsetAsync(cnt, 0, (size_t)(NKEYS + 1) * 4, stream);
        fused_transpose_scatter<<<NTILES + eb, 256, 0, stream>>>(
            inputs, inT, vals, rows, cols, cnt, pairs, tail, nnz);
        spmm_axpy_kernel<<<(NF / FT) * (BATCH_TOTAL / BT), NT_MAIN, 0, stream>>>(
            inT, pairs, cnt, tail, bias, out);
    } else {
        // Fallback: R2 structure (needs ~2.1 MB of ws).
        int* cnt1   = (int*)ws;
        int* cursor = cnt1 + NF;
        int* rptr   = cursor + NF;
        size_t fb_off = ((size_t)(3 * NF) * 4 + 15) & ~(size_t)15;
        int*   srow = (int*)(ws + fb_off);
        int*   scol = srow + nnz;
        float* sval = (float*)(scol + nnz);
        (void)hipMemsetAsync(cnt1, 0, (size_t)NF * 4, stream);
        init_out_kernel<<<2048, 256, 0, stream>>>(out, bias);
        hist_kernel<<<eb, 256, 0, stream>>>(rows, cnt1, nnz);
        scan_kernel<<<1, 1024, 0, stream>>>(cnt1, rptr, cursor);
        scatter3_kernel<<<eb, 256, 0, stream>>>(vals, rows, cols, cursor,
                                                sval, scol, srow, nnz);
        spmm_csr_fb_kernel<<<BATCH_TOTAL / TILE_B_FB, 512, 0, stream>>>(
            inputs, sval, scol, srow, out, nnz);
    }
}